// Round 2
// baseline (284.996 us; speedup 1.0000x reference)
//
#include <hip/hip_runtime.h>
#include <stdint.h>

#define NN 16384
#define NE 128

typedef __attribute__((ext_vector_type(8))) short bf16x8;
typedef __attribute__((ext_vector_type(4))) float f32x4;

__device__ __forceinline__ uint32_t pack_bf16_2(float a, float b){
  union { float f; uint32_t u; } ua, ub;
  ua.f = a; ub.f = b;
  uint32_t x = ua.u, y = ub.u;
  x = (x + 0x7fffu + ((x >> 16) & 1u)) >> 16;   // RNE
  y = (y + 0x7fffu + ((y >> 16) & 1u)) >> 16;
  return (x & 0xffffu) | (y << 16);
}

// A [NN][NE] fp32 -> Ab [NN][NE] bf16
__global__ void conv_a_kernel(const float4* __restrict__ A, uint4* __restrict__ Ab){
  size_t t = (size_t)blockIdx.x * blockDim.x + threadIdx.x;
  float4 a = A[2*t], b = A[2*t+1];
  uint4 o;
  o.x = pack_bf16_2(a.x, a.y);
  o.y = pack_bf16_2(a.z, a.w);
  o.z = pack_bf16_2(b.x, b.y);
  o.w = pack_bf16_2(b.z, b.w);
  Ab[t] = o;
}

// B [NE][NN] fp32 + W[NE] -> Bt [NN][NE] bf16, Bt[n][k] = bf16(W[k]*B[k][n])
__global__ void conv_bt_kernel(const float* __restrict__ B, const float* __restrict__ W,
                               uint4* __restrict__ Bt){
  int n = blockIdx.x * 256 + threadIdx.x;
  #pragma unroll
  for (int kc = 0; kc < 16; ++kc){
    float f[8];
    #pragma unroll
    for (int j = 0; j < 8; ++j){
      int k = kc*8 + j;
      f[j] = W[k] * B[(size_t)k * NN + n];    // coalesced along n
    }
    uint4 o;
    o.x = pack_bf16_2(f[0], f[1]);
    o.y = pack_bf16_2(f[2], f[3]);
    o.z = pack_bf16_2(f[4], f[5]);
    o.w = pack_bf16_2(f[6], f[7]);
    Bt[(size_t)n * 16 + kc] = o;
  }
}

// 128x128 tile, 4 waves (2x2), 64x64 per wave, full K=128 in LDS.
// Operand LDS: 16B chunks, physical slot (row, g) holds logical chunk g^(row&7)
// (XOR swizzle -> conflict-free ds_read_b128 per G4).
// Epilogue: acc -> LDS (132-float row stride: dword writes land 2 lanes/bank = free)
// -> fully-coalesced float4 global stores (512B contiguous per 32 lanes).
__launch_bounds__(256, 2)
__global__ void gemm_kernel(const uint4* __restrict__ Ab, const uint4* __restrict__ Bt,
                            float* __restrict__ C){
  __shared__ uint4 lds[4224];            // 67.6 KB: operands use [0..4095], epilogue uses all
  const int tid  = threadIdx.x;
  const int lane = tid & 63;
  const int bid  = blockIdx.x;
  const int m0 = (bid & 127) << 7;       // consecutive bids share the Bt panel (L2 reuse)
  const int n0 = (bid >> 7) << 7;

  // stage both tiles: 16 chunk-copies per thread, swizzled on the ds_write side
  #pragma unroll
  for (int i = 0; i < 8; ++i){
    int cid = (i << 8) + tid;            // 0..2047 : row = cid>>4, g = cid&15
    int row = cid >> 4;
    int gs  = (cid & 15) ^ (row & 7);    // source logical chunk for this physical slot
    lds[cid]        = Ab[(((size_t)(m0 + row)) << 4) + gs];
    lds[2048 + cid] = Bt[(((size_t)(n0 + row)) << 4) + gs];
  }
  __syncthreads();

  const int w   = tid >> 6;
  const int wm  = (w >> 1) << 6;         // wave's 64-row block
  const int wn  = (w & 1) << 6;          // wave's 64-col block
  const int l15 = lane & 15;
  const int l4  = lane >> 4;

  f32x4 acc[4][4];
  #pragma unroll
  for (int i = 0; i < 4; ++i)
    #pragma unroll
    for (int j = 0; j < 4; ++j)
      acc[i][j] = (f32x4){0.f, 0.f, 0.f, 0.f};

  #pragma unroll
  for (int ks = 0; ks < 4; ++ks){        // K = 4 x 32
    bf16x8 af[4], bfr[4];
    const int c = (ks << 2) + l4;        // logical 16B chunk = 8 k-values
    #pragma unroll
    for (int mt = 0; mt < 4; ++mt){
      int row = wm + (mt << 4) + l15;    // A row (lane&15 = M index)
      af[mt] = *reinterpret_cast<const bf16x8*>(&lds[(row << 4) + (c ^ (row & 7))]);
    }
    #pragma unroll
    for (int nt = 0; nt < 4; ++nt){
      int row = wn + (nt << 4) + l15;    // Bt row (lane&15 = N index)
      bfr[nt] = *reinterpret_cast<const bf16x8*>(&lds[2048 + (row << 4) + (c ^ (row & 7))]);
    }
    #pragma unroll
    for (int mt = 0; mt < 4; ++mt)
      #pragma unroll
      for (int nt = 0; nt < 4; ++nt)
        acc[mt][nt] = __builtin_amdgcn_mfma_f32_16x16x32_bf16(af[mt], bfr[nt], acc[mt][nt], 0, 0, 0);
  }

  // ---- epilogue: transpose through LDS for coalesced float4 stores ----
  __syncthreads();                       // all operand ds_reads done before overwrite
  float* lf = (float*)lds;               // [128][132] padded tile
  #pragma unroll
  for (int mt = 0; mt < 4; ++mt){
    #pragma unroll
    for (int j = 0; j < 4; ++j){
      int r = wm + (mt << 4) + (l4 << 2) + j;   // C/D layout: col=lane&15, row=(lane>>4)*4+reg
      #pragma unroll
      for (int nt = 0; nt < 4; ++nt)
        lf[r * 132 + wn + (nt << 4) + l15] = acc[mt][nt][j];
    }
  }
  __syncthreads();
  #pragma unroll
  for (int i = 0; i < 16; ++i){
    int chunk = (i << 8) + tid;          // 4096 float4 chunks of the 128x128 tile
    int r  = chunk >> 5;                 // tile row
    int c4 = (chunk & 31) << 2;          // float col (16B-aligned: 132*4 & c4*4 both %16==0)
    float4 v = *reinterpret_cast<const float4*>(&lf[r * 132 + c4]);
    *reinterpret_cast<float4*>(&C[(size_t)(m0 + r) * NN + (size_t)(n0 + c4)]) = v;
  }
}

// correctness fallback if workspace is too small (fp32 vector math, slow but exact-path)
__global__ void gemm_fallback(const float* __restrict__ A, const float* __restrict__ B,
                              const float* __restrict__ W, float* __restrict__ C){
  int n = blockIdx.x * 16 + threadIdx.x;
  int m = blockIdx.y * 16 + threadIdx.y;
  float acc = 0.f;
  for (int k = 0; k < NE; ++k)
    acc += A[(size_t)m * NE + k] * (W[k] * B[(size_t)k * NN + n]);
  C[(size_t)m * NN + n] = acc;
}

extern "C" void kernel_launch(void* const* d_in, const int* in_sizes, int n_in,
                              void* d_out, int out_size, void* d_ws, size_t ws_size,
                              hipStream_t stream){
  const float* A = (const float*)d_in[0];   // DV2_H [NN][NE]
  const float* B = (const float*)d_in[1];   // invDE_HT_DV2 [NE][NN]
  const float* W = (const float*)d_in[2];   // [NE]
  float* C = (float*)d_out;                 // [NN][NN] fp32

  const size_t need = (size_t)NN * NE * 2 * 2;   // Ab + Bt, 8 MB
  if (ws_size >= need){
    uint4* Ab = (uint4*)d_ws;
    uint4* Bt = (uint4*)((char*)d_ws + (size_t)NN * NE * 2);
    conv_a_kernel<<<NN * NE / (256 * 8), 256, 0, stream>>>((const float4*)A, Ab);
    conv_bt_kernel<<<NN / 256, 256, 0, stream>>>(B, W, Bt);
    gemm_kernel<<<(NN / 128) * (NN / 128), 256, 0, stream>>>(Ab, Bt, C);
  } else {
    dim3 g(NN / 16, NN / 16), b(16, 16);
    gemm_fallback<<<g, b, 0, stream>>>(A, B, W, C);
  }
}

// Round 3
// 226.258 us; speedup vs baseline: 1.2596x; 1.2596x over previous
//
#include <hip/hip_runtime.h>
#include <stdint.h>

#define NN 16384
#define NE 128

typedef __attribute__((ext_vector_type(8))) short bf16x8;
typedef __attribute__((ext_vector_type(4))) float f32x4;

__device__ __forceinline__ uint32_t pack_bf16_2(float a, float b){
  union { float f; uint32_t u; } ua, ub;
  ua.f = a; ub.f = b;
  uint32_t x = ua.u, y = ub.u;
  x = (x + 0x7fffu + ((x >> 16) & 1u)) >> 16;   // RNE
  y = (y + 0x7fffu + ((y >> 16) & 1u)) >> 16;
  return (x & 0xffffu) | (y << 16);
}

// A [NN][NE] fp32 -> Ab [NN][NE] bf16
__global__ void conv_a_kernel(const float4* __restrict__ A, uint4* __restrict__ Ab){
  size_t t = (size_t)blockIdx.x * blockDim.x + threadIdx.x;
  float4 a = A[2*t], b = A[2*t+1];
  uint4 o;
  o.x = pack_bf16_2(a.x, a.y);
  o.y = pack_bf16_2(a.z, a.w);
  o.z = pack_bf16_2(b.x, b.y);
  o.w = pack_bf16_2(b.z, b.w);
  Ab[t] = o;
}

// B [NE][NN] fp32 + W[NE] -> Bt [NN][NE] bf16, Bt[n][k] = bf16(W[k]*B[k][n])
__global__ void conv_bt_kernel(const float* __restrict__ B, const float* __restrict__ W,
                               uint4* __restrict__ Bt){
  int n = blockIdx.x * 256 + threadIdx.x;
  #pragma unroll
  for (int kc = 0; kc < 16; ++kc){
    float f[8];
    #pragma unroll
    for (int j = 0; j < 8; ++j){
      int k = kc*8 + j;
      f[j] = W[k] * B[(size_t)k * NN + n];    // coalesced along n
    }
    uint4 o;
    o.x = pack_bf16_2(f[0], f[1]);
    o.y = pack_bf16_2(f[2], f[3]);
    o.z = pack_bf16_2(f[4], f[5]);
    o.w = pack_bf16_2(f[6], f[7]);
    Bt[(size_t)n * 16 + kc] = o;
  }
}

// 128x128 tile, 4 waves (2x2), 64x64 per wave, full K=128 in LDS.
// Operand LDS: 16B chunks, physical slot (row, g) holds logical chunk g^(row&7)
// (XOR swizzle -> conflict-free ds_read_b128 per G4).
// Grid swizzle: GM=16 m-tiles per group; 16 consecutive bids share one Bt panel,
// the group's 512KB Ab slice stays L2-hot across all 128 n-panels -> operand
// HBM re-fetch ~0.5GB -> ~40MB (round-2 post-mortem: total-traffic bound).
__launch_bounds__(256, 2)
__global__ void gemm_kernel(const uint4* __restrict__ Ab, const uint4* __restrict__ Bt,
                            float* __restrict__ C){
  __shared__ uint4 lds[4096];            // 64 KB: [0..2047] A-tile, [2048..4095] B-tile
  const int tid  = threadIdx.x;
  const int lane = tid & 63;
  const int bid  = blockIdx.x;
  const int grp  = bid >> 11;            // bid / (16*128): 8 groups
  const int r    = bid & 2047;
  const int m0   = (((grp << 4) + (r & 15)) << 7);   // m iterates fastest within group
  const int n0   = ((r >> 4) << 7);

  // stage both tiles: 16 chunk-copies per thread, swizzled on the ds_write side
  #pragma unroll
  for (int i = 0; i < 8; ++i){
    int cid = (i << 8) + tid;            // 0..2047 : row = cid>>4, g = cid&15
    int row = cid >> 4;
    int gs  = (cid & 15) ^ (row & 7);    // source logical chunk for this physical slot
    lds[cid]        = Ab[(((size_t)(m0 + row)) << 4) + gs];
    lds[2048 + cid] = Bt[(((size_t)(n0 + row)) << 4) + gs];
  }
  __syncthreads();

  const int w   = tid >> 6;
  const int wm  = (w >> 1) << 6;         // wave's 64-row block
  const int wn  = (w & 1) << 6;          // wave's 64-col block
  const int l15 = lane & 15;
  const int l4  = lane >> 4;

  f32x4 acc[4][4];
  #pragma unroll
  for (int i = 0; i < 4; ++i)
    #pragma unroll
    for (int j = 0; j < 4; ++j)
      acc[i][j] = (f32x4){0.f, 0.f, 0.f, 0.f};

  #pragma unroll
  for (int ks = 0; ks < 4; ++ks){        // K = 4 x 32
    bf16x8 af[4], bfr[4];
    const int c = (ks << 2) + l4;        // logical 16B chunk = 8 k-values
    #pragma unroll
    for (int mt = 0; mt < 4; ++mt){
      int row = wm + (mt << 4) + l15;    // A row (lane&15 = M index)
      af[mt] = *reinterpret_cast<const bf16x8*>(&lds[(row << 4) + (c ^ (row & 7))]);
    }
    #pragma unroll
    for (int nt = 0; nt < 4; ++nt){
      int row = wn + (nt << 4) + l15;    // Bt row (lane&15 = N index)
      bfr[nt] = *reinterpret_cast<const bf16x8*>(&lds[2048 + (row << 4) + (c ^ (row & 7))]);
    }
    #pragma unroll
    for (int mt = 0; mt < 4; ++mt)
      #pragma unroll
      for (int nt = 0; nt < 4; ++nt)
        acc[mt][nt] = __builtin_amdgcn_mfma_f32_16x16x32_bf16(af[mt], bfr[nt], acc[mt][nt], 0, 0, 0);
  }

  // C/D layout: col = lane&15, row = (lane>>4)*4 + reg. Direct dword stores
  // (round-2 showed the LDS-transpose epilogue regresses: barriers not hideable
  // at 2 blocks/CU). 4 consecutive insts cover a contiguous 256B span per row.
  #pragma unroll
  for (int mt = 0; mt < 4; ++mt){
    #pragma unroll
    for (int j = 0; j < 4; ++j){
      size_t row = (size_t)(m0 + wm + (mt << 4) + (l4 << 2) + j);
      float* crow = C + row * NN + (size_t)(n0 + wn + l15);
      #pragma unroll
      for (int nt = 0; nt < 4; ++nt)
        crow[nt << 4] = acc[mt][nt][j];
    }
  }
}

// correctness fallback if workspace is too small (fp32 vector math, slow but exact-path)
__global__ void gemm_fallback(const float* __restrict__ A, const float* __restrict__ B,
                              const float* __restrict__ W, float* __restrict__ C){
  int n = blockIdx.x * 16 + threadIdx.x;
  int m = blockIdx.y * 16 + threadIdx.y;
  float acc = 0.f;
  for (int k = 0; k < NE; ++k)
    acc += A[(size_t)m * NE + k] * (W[k] * B[(size_t)k * NN + n]);
  C[(size_t)m * NN + n] = acc;
}

extern "C" void kernel_launch(void* const* d_in, const int* in_sizes, int n_in,
                              void* d_out, int out_size, void* d_ws, size_t ws_size,
                              hipStream_t stream){
  const float* A = (const float*)d_in[0];   // DV2_H [NN][NE]
  const float* B = (const float*)d_in[1];   // invDE_HT_DV2 [NE][NN]
  const float* W = (const float*)d_in[2];   // [NE]
  float* C = (float*)d_out;                 // [NN][NN] fp32

  const size_t need = (size_t)NN * NE * 2 * 2;   // Ab + Bt, 8 MB
  if (ws_size >= need){
    uint4* Ab = (uint4*)d_ws;
    uint4* Bt = (uint4*)((char*)d_ws + (size_t)NN * NE * 2);
    conv_a_kernel<<<NN * NE / (256 * 8), 256, 0, stream>>>((const float4*)A, Ab);
    conv_bt_kernel<<<NN / 256, 256, 0, stream>>>(B, W, Bt);
    gemm_kernel<<<(NN / 128) * (NN / 128), 256, 0, stream>>>(Ab, Bt, C);
  } else {
    dim3 g(NN / 16, NN / 16), b(16, 16);
    gemm_fallback<<<g, b, 0, stream>>>(A, B, W, C);
  }
}